// Round 13
// baseline (218.701 us; speedup 1.0000x reference)
//
#include <hip/hip_runtime.h>
#include <hip/hip_bf16.h>
#include <cstdint>

#define THREADS 256

typedef __attribute__((ext_vector_type(8))) short bf16x8;
typedef __attribute__((ext_vector_type(4))) float f32x4;
typedef __attribute__((ext_vector_type(2))) unsigned int u32x2;

__device__ __forceinline__ void load_lds16(const void* g, void* l) {
    __builtin_amdgcn_global_load_lds(
        (const __attribute__((address_space(1))) unsigned int*)g,
        (__attribute__((address_space(3))) unsigned int*)l, 16, 0, 0);
}

__device__ __forceinline__ unsigned short f2bf(float x) {
    __hip_bfloat16 hb = __float2bfloat16(x);
    return *(unsigned short*)&hb;
}

// pack two f32 -> one u32 of 2x bf16 (lo in low half)
__device__ __forceinline__ unsigned cvt_pk_bf16(float lo, float hi) {
    unsigned r;
    asm("v_cvt_pk_bf16_f32 %0, %1, %2" : "=v"(r) : "v"(lo), "v"(hi));
    return r;
}

__device__ __forceinline__ float fexp2(float x) {
#if __has_builtin(__builtin_amdgcn_exp2f)
    return __builtin_amdgcn_exp2f(x);
#else
    return exp2f(x);
#endif
}

// distance-32 exchange: lo = [lo_low32 | hi_low32], hi = [lo_high32 | hi_high32]
__device__ __forceinline__ void swap32(unsigned& lo, unsigned& hi) {
#if __has_builtin(__builtin_amdgcn_permlane32_swap)
    u32x2 r = __builtin_amdgcn_permlane32_swap(lo, hi, false, false);
    lo = r[0]; hi = r[1];
#else
    unsigned plo = (unsigned)__shfl_xor((int)lo, 32, 64);
    unsigned phi = (unsigned)__shfl_xor((int)hi, 32, 64);
    bool up = (threadIdx.x & 32) != 0;
    unsigned nlo = up ? phi : lo;
    unsigned nhi = up ? hi : plo;
    lo = nlo; hi = nhi;
#endif
}

// distance-16 exchange: a's odd 16-rows <-> c's even 16-rows (v_permlane16_swap_b32)
__device__ __forceinline__ void swap16(unsigned& a, unsigned& c) {
#if __has_builtin(__builtin_amdgcn_permlane16_swap)
    u32x2 r = __builtin_amdgcn_permlane16_swap(a, c, false, false);
    a = r[0]; c = r[1];
#else
    unsigned as = (unsigned)__shfl_xor((int)a, 16, 64);
    unsigned cs = (unsigned)__shfl_xor((int)c, 16, 64);
    bool odd = (threadIdx.x & 16) != 0;
    unsigned na = odd ? cs : a;   // odd rows of a take c's even rows
    unsigned nc = odd ? c  : as;  // even rows of c take a's odd rows
    a = na; c = nc;
#endif
}

// ---------------------------------------------------------------------------
// Fused fp32 -> bf16 cast of the six GEMM inputs. (r13 verbatim)
// ---------------------------------------------------------------------------
__global__ __launch_bounds__(THREADS)
void cast_inputs(const float* __restrict__ xq, const float* __restrict__ xkv,
                 const float* __restrict__ wq, const float* __restrict__ wk,
                 const float* __restrict__ wv, const float* __restrict__ wo,
                 unsigned short* __restrict__ oq, unsigned short* __restrict__ okv,
                 unsigned short* __restrict__ owq, unsigned short* __restrict__ owk,
                 unsigned short* __restrict__ owv, unsigned short* __restrict__ owo) {
    const unsigned n0 = 524288, n1 = 1572864, n2 = 262144, n3 = 196608, n4 = 196608;
    unsigned i = blockIdx.x * THREADS + threadIdx.x;  // < 3014656
    const float* src; unsigned short* dst; unsigned off;
    if (i < n0)                    { src = xq;  dst = oq;  off = i; }
    else if (i < n0+n1)            { src = xkv; dst = okv; off = i - n0; }
    else if (i < n0+n1+n2)         { src = wq;  dst = owq; off = i - n0 - n1; }
    else if (i < n0+n1+n2+n3)      { src = wk;  dst = owk; off = i - n0 - n1 - n2; }
    else if (i < n0+n1+n2+n3+n4)   { src = wv;  dst = owv; off = i - n0 - n1 - n2 - n3; }
    else                           { src = wo;  dst = owo; off = i - n0 - n1 - n2 - n3 - n4; }
    float4 v = *(const float4*)(src + (size_t)off * 4);
    ushort4 o;
    o.x = f2bf(v.x); o.y = f2bf(v.y); o.z = f2bf(v.z); o.w = f2bf(v.w);
    *(ushort4*)(dst + (size_t)off * 4) = o;
}

// ---------------------------------------------------------------------------
// MERGED projection dispatch (grid 1024).
// KV tiles grown 128x128 -> 256x128 at the same 4 waves.
//  Round-10 verdict: XCD swizzle was time-neutral -> proj is NOT BW-bound;
//  it's limited by the 2-barrier K-loop's MFMA:overhead ratio. Each wave now
//  owns a 128x64 output (8x4 f32x4 acc): 64 MFMA/wave between the same two
//  barriers (2x previous), and staging bytes/FLOP drop 25%
//  (48KB per 256x128x64-step vs 32KB per 128x128x64-step).
//  512 KV blocks (2/CU exact, no tail) + 512 Q blocks (64^2 path, measured
//  best). XCD-chunked bijection kept: xcd=bid&7, m=(xcd<<2)|(bid>>7),
//  n=(bid>>3)&15  (512 = 8 XCDs x 4 m-groups x 16 n-tiles).
//  Row-pair XOR key (l15>>1)&7 is row-offset-invariant (wm*128, mt*16 are
//  multiples of 16), so all staging/read swizzle formulas carry over.
//  Epilogue addresses are per-(token,feature) identical to r13's verified
//  mapping (rbase&255 = wm*128; b,h constant across the 128-row wave span).
// ---------------------------------------------------------------------------
__global__ __launch_bounds__(THREADS)
void gemm_proj(const unsigned short* __restrict__ xkv, const unsigned short* __restrict__ wkv,
               unsigned short* __restrict__ Kn, unsigned short* __restrict__ Vt,
               const unsigned short* __restrict__ xq, const unsigned short* __restrict__ wq,
               unsigned short* __restrict__ Qout) {
    __shared__ __align__(16) unsigned short As[256 * 64];   // 32 KB
    __shared__ __align__(16) unsigned short Bs[128 * 64];   // 16 KB

    const int t    = threadIdx.x;
    const int w    = t >> 6;
    const int lane = t & 63;
    const int l15  = lane & 15;
    const int quad = lane >> 4;
    const int wm   = w & 1;
    const int wn   = w >> 1;

    if (blockIdx.x < 512) {
        // ---- KV: 256x128 tile ----
        const int xcd = blockIdx.x & 7;
        const int m   = (xcd << 2) | (blockIdx.x >> 7);   // 0..31  (bM group)
        const int n   = (blockIdx.x >> 3) & 15;           // 0..15  (bN tile)
        const int bM = m * 256;
        const int bN = n * 128;
        const int Kd = 768;

        const int srow = t >> 3;                          // 0..31
        const int scol = ((t & 7) ^ ((t >> 4) & 7)) << 3;
        const unsigned short* ga = xkv + (size_t)(bM + srow) * Kd + scol;
        const unsigned short* gb = wkv + (size_t)(bN + srow) * Kd + scol;
        const int lbase = w * 512;

        const int xr = (l15 >> 1) & 7;
        int aoff[2][8], boff[2][4];
#pragma unroll
        for (int kk = 0; kk < 2; ++kk) {
#pragma unroll
            for (int mt = 0; mt < 8; ++mt)
                aoff[kk][mt] = (wm * 128 + mt * 16 + l15) * 64 + (((kk * 4 + quad) ^ xr) << 3);
#pragma unroll
            for (int nt = 0; nt < 4; ++nt)
                boff[kk][nt] = (wn * 64 + nt * 16 + l15) * 64 + (((kk * 4 + quad) ^ xr) << 3);
        }

        f32x4 acc[8][4];
#pragma unroll
        for (int mt = 0; mt < 8; ++mt)
#pragma unroll
            for (int nt = 0; nt < 4; ++nt)
#pragma unroll
                for (int r = 0; r < 4; ++r) acc[mt][nt][r] = 0.f;

        for (int k0 = 0; k0 < Kd; k0 += 64) {
            __syncthreads();
#pragma unroll
            for (int it = 0; it < 8; ++it)
                load_lds16(ga + (size_t)it * 32 * Kd + k0, &As[lbase + it * 2048]);
#pragma unroll
            for (int it = 0; it < 4; ++it)
                load_lds16(gb + (size_t)it * 32 * Kd + k0, &Bs[lbase + it * 2048]);
            __syncthreads();

#pragma unroll
            for (int kk = 0; kk < 2; ++kk) {
                bf16x8 bf[4];
#pragma unroll
                for (int nt = 0; nt < 4; ++nt) bf[nt] = *(const bf16x8*)&Bs[boff[kk][nt]];
#pragma unroll
                for (int mt = 0; mt < 8; ++mt) {
                    bf16x8 af = *(const bf16x8*)&As[aoff[kk][mt]];
#pragma unroll
                    for (int nt = 0; nt < 4; ++nt)
                        acc[mt][nt] = __builtin_amdgcn_mfma_f32_16x16x32_bf16(af, bf[nt], acc[mt][nt], 0, 0, 0);
                }
            }
        }

        const int rbase = bM + wm * 128;
        const int b  = rbase >> 12;
        const int h  = (rbase & 4095) >> 8;
        if (bN < 1024) {
            const int G = (bN + wn * 64) >> 6;
            unsigned short* kp = Kn + (size_t)(b * 16 + h) * 262144 + (size_t)G * 16384 + l15;
#pragma unroll
            for (int mt = 0; mt < 8; ++mt)
#pragma unroll
                for (int r = 0; r < 4; ++r) {
                    int u = (rbase & 255) + mt * 16 + quad * 4 + r;
                    unsigned short* cp = kp + (size_t)u * 64;
#pragma unroll
                    for (int nt = 0; nt < 4; ++nt) cp[nt * 16] = f2bf(acc[mt][nt][r]);
                }
        } else {
            const int Gv = (bN - 1024 + wn * 64) >> 6;
            unsigned short* vp = Vt + (size_t)(b * 16 + h) * 262144 + (size_t)Gv * 256;
#pragma unroll
            for (int nt = 0; nt < 4; ++nt) {
                int d = nt * 16 + l15;
#pragma unroll
                for (int mt = 0; mt < 8; ++mt) {
                    int u = (rbase & 255) + mt * 16 + quad * 4;
                    ushort4 pk;
                    pk.x = f2bf(acc[mt][nt][0]);
                    pk.y = f2bf(acc[mt][nt][1]);
                    pk.z = f2bf(acc[mt][nt][2]);
                    pk.w = f2bf(acc[mt][nt][3]);
                    *(ushort4*)(vp + (size_t)d * 4096 + u) = pk;
                }
            }
        }
    } else {
        // ---- Q: 64x64 tile, 512 blocks (r13 verbatim) ----
        const int id = blockIdx.x - 512;            // 0..511
        const int bN = (id & 15) * 64;
        const int bM = (id >> 4) * 64;
        const int Kd = 1024, N = 1024;

        const int srow = t >> 3;
        const int scol = ((t & 7) ^ ((t >> 3) & 7)) << 3;
        const unsigned short* ga = xq + (size_t)(bM + srow) * Kd + scol;
        const unsigned short* gb = wq + (size_t)(bN + srow) * Kd + scol;
        const int lbase = w * 512;

        int aoff[2][2], boff[2][2];
#pragma unroll
        for (int kk = 0; kk < 2; ++kk)
#pragma unroll
            for (int mt = 0; mt < 2; ++mt) {
                aoff[kk][mt] = (wm * 32 + mt * 16 + l15) * 64 + (((kk * 4 + quad) ^ (l15 & 7)) << 3);
                boff[kk][mt] = (wn * 32 + mt * 16 + l15) * 64 + (((kk * 4 + quad) ^ (l15 & 7)) << 3);
            }

        f32x4 acc[2][2];
#pragma unroll
        for (int mt = 0; mt < 2; ++mt)
#pragma unroll
            for (int nt = 0; nt < 2; ++nt)
#pragma unroll
                for (int r = 0; r < 4; ++r) acc[mt][nt][r] = 0.f;

        for (int k0 = 0; k0 < Kd; k0 += 64) {
            __syncthreads();
#pragma unroll
            for (int it = 0; it < 2; ++it) {
                load_lds16(ga + (size_t)it * 32 * Kd + k0, &As[lbase + it * 2048]);
                load_lds16(gb + (size_t)it * 32 * Kd + k0, &Bs[lbase + it * 2048]);
            }
            __syncthreads();

#pragma unroll
            for (int kk = 0; kk < 2; ++kk) {
                bf16x8 af[2], bf[2];
#pragma unroll
                for (int mt = 0; mt < 2; ++mt) af[mt] = *(const bf16x8*)&As[aoff[kk][mt]];
#pragma unroll
                for (int nt = 0; nt < 2; ++nt) bf[nt] = *(const bf16x8*)&Bs[boff[kk][nt]];
#pragma unroll
                for (int mt = 0; mt < 2; ++mt)
#pragma unroll
                    for (int nt = 0; nt < 2; ++nt)
                        acc[mt][nt] = __builtin_amdgcn_mfma_f32_16x16x32_bf16(af[mt], bf[nt], acc[mt][nt], 0, 0, 0);
            }
        }

#pragma unroll
        for (int mt = 0; mt < 2; ++mt)
#pragma unroll
            for (int r = 0; r < 4; ++r) {
                int row = bM + wm * 32 + mt * 16 + quad * 4 + r;
                int col = bN + wn * 32 + l15;
                unsigned short* cp = Qout + (size_t)row * N + col;
#pragma unroll
                for (int nt = 0; nt < 2; ++nt) cp[nt * 16] = f2bf(acc[mt][nt][r]);
            }
    }
}

// ---------------------------------------------------------------------------
// 64x64-tile bf16 MFMA GEMM (Wo projection). r13 verbatim — 512-block
// 64x64 beats the 128-block 128x128 variant at this size (round-7 data).
// ---------------------------------------------------------------------------
template <bool OUTF32>
__global__ __launch_bounds__(THREADS)
void gemm_bf16_nt64(const unsigned short* __restrict__ A, const unsigned short* __restrict__ W,
                    void* __restrict__ Cout, int M, int N, int Kd) {
    __shared__ __align__(16) unsigned short As[64 * 64];
    __shared__ __align__(16) unsigned short Bs[64 * 64];

    const int t    = threadIdx.x;
    const int w    = t >> 6;
    const int lane = t & 63;
    const int l15  = lane & 15;
    const int quad = lane >> 4;
    const int wm   = w & 1;
    const int wn   = w >> 1;
    const int bM = blockIdx.y * 64;
    const int bN = blockIdx.x * 64;

    const int srow = t >> 3;
    const int scol = ((t & 7) ^ ((t >> 3) & 7)) << 3;
    const unsigned short* ga = A + (size_t)(bM + srow) * Kd + scol;
    const unsigned short* gb = W + (size_t)(bN + srow) * Kd + scol;
    const int lbase = w * 512;

    int aoff[2][2], boff[2][2];
#pragma unroll
    for (int kk = 0; kk < 2; ++kk)
#pragma unroll
        for (int mt = 0; mt < 2; ++mt) {
            aoff[kk][mt] = (wm * 32 + mt * 16 + l15) * 64 + (((kk * 4 + quad) ^ (l15 & 7)) << 3);
            boff[kk][mt] = (wn * 32 + mt * 16 + l15) * 64 + (((kk * 4 + quad) ^ (l15 & 7)) << 3);
        }

    f32x4 acc[2][2];
#pragma unroll
    for (int mt = 0; mt < 2; ++mt)
#pragma unroll
        for (int nt = 0; nt < 2; ++nt)
#pragma unroll
            for (int r = 0; r < 4; ++r) acc[mt][nt][r] = 0.f;

    for (int k0 = 0; k0 < Kd; k0 += 64) {
        __syncthreads();
#pragma unroll
        for (int it = 0; it < 2; ++it) {
            load_lds16(ga + (size_t)it * 32 * Kd + k0, &As[lbase + it * 2048]);
            load_lds16(gb + (size_t)it * 32 * Kd + k0, &Bs[lbase + it * 2048]);
        }
        __syncthreads();

#pragma unroll
        for (int kk = 0; kk < 2; ++kk) {
            bf16x8 af[2], bf[2];
#pragma unroll
            for (int mt = 0; mt < 2; ++mt) af[mt] = *(const bf16x8*)&As[aoff[kk][mt]];
#pragma unroll
            for (int nt = 0; nt < 2; ++nt) bf[nt] = *(const bf16x8*)&Bs[boff[kk][nt]];
#pragma unroll
            for (int mt = 0; mt < 2; ++mt)
#pragma unroll
                for (int nt = 0; nt < 2; ++nt)
                    acc[mt][nt] = __builtin_amdgcn_mfma_f32_16x16x32_bf16(af[mt], bf[nt], acc[mt][nt], 0, 0, 0);
        }
    }

#pragma unroll
    for (int mt = 0; mt < 2; ++mt)
#pragma unroll
        for (int r = 0; r < 4; ++r) {
            int row = bM + wm * 32 + mt * 16 + quad * 4 + r;
            int col = bN + wn * 32 + l15;
            if (OUTF32) {
                float* cp = (float*)Cout + (size_t)row * N + col;
#pragma unroll
                for (int nt = 0; nt < 2; ++nt) cp[nt * 16] = acc[mt][nt][r];
            } else {
                unsigned short* cp = (unsigned short*)Cout + (size_t)row * N + col;
#pragma unroll
                for (int nt = 0; nt < 2; ++nt) cp[nt * 16] = f2bf(acc[mt][nt][r]);
            }
        }
}

// ---------------------------------------------------------------------------
// Flash attention v13: v10 structure + DEPTH-2 LDS DOUBLE-BUFFER.
//  (round-5/round-10 verified: ~53 us; frozen — grid-capped at 2 blocks/CU,
//  splits falsified in rounds 3-4)
// ---------------------------------------------------------------------------
__global__ __launch_bounds__(THREADS, 2)
void attn_mfma13(const unsigned short* __restrict__ Q, const unsigned short* __restrict__ K,
                 const unsigned short* __restrict__ Vt, unsigned short* __restrict__ AO) {
    extern __shared__ __align__(16) unsigned short sm[];
    // Ks buf0: [0,8192), Ks buf1: [8192,16384)
    // Vs buf0: [16384,24576), Vs buf1: [24576,32768)   (shorts; total 64 KB)
    float* OS = (float*)sm;               // epilogue overlay: 3 x [64d][68q] f32
    float* Lw = (float*)(sm + 26624);     // 256 f32

    const int bid  = blockIdx.x;          // 0..511
    const int slot = bid >> 3;
    const int qq   = slot & 15;
    const int hh   = (bid & 7) + 8 * (slot >> 4);
    const int q0 = qq * 64;
    const int h  = hh & 15;
    const int b  = hh >> 4;

    const int t    = threadIdx.x;
    const int w    = t >> 6;              // kv-quarter owner
    const int lane = t & 63;
    const int l15  = lane & 15;
    const int quad = lane >> 4;

    const unsigned short* Qh = Q + (size_t)b * 1048576 + (size_t)h * 65536 + (size_t)q0 * 64;
    const unsigned short* Kh = K + (size_t)b * 4194304 + (size_t)h * 262144;
    const unsigned short* Vh = Vt + (size_t)(b * 16 + h) * 262144;

    bf16x8 Qb[4][2];
#pragma unroll
    for (int qt = 0; qt < 4; ++qt)
#pragma unroll
        for (int kk = 0; kk < 2; ++kk)
            Qb[qt][kk] = *(const bf16x8*)(Qh + (size_t)(qt * 16 + l15) * 64 + kk * 32 + quad * 8);

    // wave-private staging pointers (v10 layout)
    const unsigned short* gKw = Kh + (size_t)(w * 32 + (lane >> 3)) * 64
                                   + (((lane & 7) ^ ((lane >> 3) & 7)) << 3);
    const unsigned short* gVw = Vh + (size_t)(lane >> 2) * 4096 + w * 32
                                   + (((lane & 3) ^ ((lane >> 2) & 3)) << 3);
    const int ldsK = w * 2048;            // + it*512 (shorts), within a K buffer
    const int ldsV = w * 2048;            // + it*512 (shorts), within a V buffer

    int koff[2][2];
#pragma unroll
    for (int kvt = 0; kvt < 2; ++kvt)
#pragma unroll
        for (int kk = 0; kk < 2; ++kk)
            koff[kvt][kk] = (w * 32 + kvt * 16 + l15) * 64 + (((kk * 4 + quad) ^ (l15 & 7)) << 3);
    int voff[4];
#pragma unroll
    for (int dt = 0; dt < 4; ++dt)
        voff[dt] = w * 2048 + (dt * 16 + l15) * 32 + ((quad ^ (l15 & 3)) << 3);

    f32x4 Oacc[4][4];
#pragma unroll
    for (int qt = 0; qt < 4; ++qt)
#pragma unroll
        for (int dt = 0; dt < 4; ++dt)
#pragma unroll
            for (int r = 0; r < 4; ++r) Oacc[qt][dt][r] = 0.f;
    float lsum[4] = {0.f, 0.f, 0.f, 0.f};

    // exp(S/64) == exp2(S * log2(e)/64): single mul feeding v_exp_f32
    const float e2s = 0.022542110013890053f;

    // ---- prologue: stage chunks 0 and 1 (16 loads in flight = steady state) ----
#pragma unroll
    for (int it = 0; it < 4; ++it)
        load_lds16(gKw + it * 512, &sm[ldsK + it * 512]);                       // K0 -> buf0
#pragma unroll
    for (int it = 0; it < 4; ++it)
        load_lds16(gVw + (size_t)it * 65536, &sm[16384 + ldsV + it * 512]);     // V0 -> buf0
#pragma unroll
    for (int it = 0; it < 4; ++it)
        load_lds16(gKw + 8192 + it * 512, &sm[8192 + ldsK + it * 512]);         // K1 -> buf1
#pragma unroll
    for (int it = 0; it < 4; ++it)
        load_lds16(gVw + 128 + (size_t)it * 65536, &sm[24576 + ldsV + it * 512]); // V1 -> buf1

    for (int kc = 0; kc < 32; ++kc) {
        const int buf = kc & 1;
        const int kn2 = (kc + 2) & 31;   // wrap keeps prefetch in-bounds
        const int kbase = buf * 8192;          // K buffer base (shorts)
        const int vbase = 16384 + buf * 8192;  // V buffer base (shorts)

        // queue (oldest->newest): K(kc),V(kc),K(kc+1),V(kc+1) = 16 loads
        asm volatile("s_waitcnt vmcnt(12)" ::: "memory");  // K(kc) landed

        // read ALL K frags, retire, then prefetch K(kc+2) into this (now dead) buffer
        bf16x8 ka0 = *(const bf16x8*)&sm[kbase + koff[0][0]];
        bf16x8 kb0 = *(const bf16x8*)&sm[kbase + koff[0][1]];
        bf16x8 ka1 = *(const bf16x8*)&sm[kbase + koff[1][0]];
        bf16x8 kb1 = *(const bf16x8*)&sm[kbase + koff[1][1]];
        asm volatile("s_waitcnt lgkmcnt(0)" ::: "memory"); // K frags in regs
#pragma unroll
        for (int it = 0; it < 4; ++it)
            load_lds16(gKw + (size_t)kn2 * 8192 + it * 512, &sm[kbase + ldsK + it * 512]);

        // ---- S-phase: S^T tiles, exp2, pure-permlane P transpose ----
        bf16x8 Pa[4];
#pragma unroll
        for (int qt = 0; qt < 4; ++qt) {
            f32x4 S0 = {0.f, 0.f, 0.f, 0.f};
            S0 = __builtin_amdgcn_mfma_f32_16x16x32_bf16(ka0, Qb[qt][0], S0, 0, 0, 0);
            S0 = __builtin_amdgcn_mfma_f32_16x16x32_bf16(kb0, Qb[qt][1], S0, 0, 0, 0);
            f32x4 S1 = {0.f, 0.f, 0.f, 0.f};
            S1 = __builtin_amdgcn_mfma_f32_16x16x32_bf16(ka1, Qb[qt][0], S1, 0, 0, 0);
            S1 = __builtin_amdgcn_mfma_f32_16x16x32_bf16(kb1, Qb[qt][1], S1, 0, 0, 0);
            float p0 = fexp2(S0[0] * e2s);
            float p1 = fexp2(S0[1] * e2s);
            float p2 = fexp2(S0[2] * e2s);
            float p3 = fexp2(S0[3] * e2s);
            float p4 = fexp2(S1[0] * e2s);
            float p5 = fexp2(S1[1] * e2s);
            float p6 = fexp2(S1[2] * e2s);
            float p7 = fexp2(S1[3] * e2s);
            lsum[qt] += ((p0 + p1) + (p2 + p3)) + ((p4 + p5) + (p6 + p7));
            // lane(row j = quad) holds u32 bf16-pair chunks: ca=2j cb=2j+1 cc=8+2j cd=9+2j
            unsigned ca = cvt_pk_bf16(p0, p1);
            unsigned cb = cvt_pk_bf16(p2, p3);
            unsigned cc = cvt_pk_bf16(p4, p5);
            unsigned cd = cvt_pk_bf16(p6, p7);
            // 4x4 chunk transpose entirely in permlanes (HW-verified in v12):
            swap32(ca, cc);
            swap32(cb, cd);
            swap16(ca, cc);
            swap16(cb, cd);
            union { unsigned u[4]; bf16x8 v; } pk_;
            pk_.u[0] = ca;   // chunk 4d+0
            pk_.u[1] = cb;   // chunk 4d+1
            pk_.u[2] = cc;   // chunk 4d+2
            pk_.u[3] = cd;   // chunk 4d+3
            Pa[qt] = pk_.v;  // A-frag: row=q(l15), k = kv quad*8..+7
        }

        // queue: V(kc),K(kc+1),V(kc+1),K(kc+2) = 16 loads
        asm volatile("s_waitcnt vmcnt(12)" ::: "memory");  // V(kc) landed

        // read V frags, retire, then prefetch V(kc+2) into this (now dead) buffer
        bf16x8 Vf[4];
#pragma unroll
        for (int dt = 0; dt < 4; ++dt) Vf[dt] = *(const bf16x8*)&sm[vbase + voff[dt]];
        asm volatile("s_waitcnt lgkmcnt(0)" ::: "memory"); // V frags in regs
#pragma unroll
        for (int it = 0; it < 4; ++it)
            load_lds16(gVw + (size_t)kn2 * 128 + (size_t)it * 65536, &sm[vbase + ldsV + it * 512]);

        // ---- O += P @ V over this wave's 32 kv (pure-MFMA cluster) ----
        __builtin_amdgcn_s_setprio(1);
#pragma unroll
        for (int qt = 0; qt < 4; ++qt)
#pragma unroll
            for (int dt = 0; dt < 4; ++dt)
                Oacc[qt][dt] = __builtin_amdgcn_mfma_f32_16x16x32_bf16(Pa[qt], Vf[dt], Oacc[qt][dt], 0, 0, 0);
        __builtin_amdgcn_s_setprio(0);
    }

    // ---- epilogue (v9 verbatim; first barrier drains the wrap prefetches) ----
#pragma unroll
    for (int qt = 0; qt < 4; ++qt) {
        float v = lsum[qt];
        v += __shfl_xor(v, 16);
        v += __shfl_xor(v, 32);
        lsum[qt] = v;
    }
    __syncthreads();   // (1) all waves done with Ks/Vs; DMA queue drained
    if (lane < 16) {
#pragma unroll
        for (int qt = 0; qt < 4; ++qt)
            Lw[w * 64 + qt * 16 + lane] = lsum[qt];
    }
    if (w > 0) {
        float* myOS = OS + (w - 1) * 4352;
#pragma unroll
        for (int qt = 0; qt < 4; ++qt)
#pragma unroll
            for (int dt = 0; dt < 4; ++dt)
                *(f32x4*)&myOS[(dt * 16 + l15) * 68 + qt * 16 + quad * 4] = Oacc[qt][dt];
    }
    __syncthreads();   // (2) partials + Lw visible
    if (w == 0) {
#pragma unroll
        for (int qt = 0; qt < 4; ++qt) {
            f32x4 lv = *(const f32x4*)&Lw[qt * 16 + quad * 4];
            lv += *(const f32x4*)&Lw[64 + qt * 16 + quad * 4];
            lv += *(const f32x4*)&Lw[128 + qt * 16 + quad * 4];
            lv += *(const f32x4*)&Lw[192 + qt * 16 + quad * 4];
            f32x4 inv;
#pragma unroll
            for (int r = 0; r < 4; ++r) inv[r] = 1.0f / lv[r];
#pragma unroll
            for (int dt = 0; dt < 4; ++dt) {
                f32x4 o = Oacc[qt][dt];
                int os = (dt * 16 + l15) * 68 + qt * 16 + quad * 4;
                o += *(const f32x4*)&OS[os];
                o += *(const f32x4*)&OS[4352 + os];
                o += *(const f32x4*)&OS[8704 + os];
#pragma unroll
                for (int r = 0; r < 4; ++r) {
                    int q = qt * 16 + quad * 4 + r;
                    AO[(size_t)b * 1048576 + (size_t)(q0 + q) * 1024 + (h << 6) + dt * 16 + l15]
                        = f2bf(o[r] * inv[r]);
                }
            }
        }
    }
}

// ---------------------------------------------------------------------------
extern "C" void kernel_launch(void* const* d_in, const int* in_sizes, int n_in,
                              void* d_out, int out_size, void* d_ws, size_t ws_size,
                              hipStream_t stream) {
    const float* x_q  = (const float*)d_in[0];  // (2,1024,1024)
    const float* x_kv = (const float*)d_in[1];  // (2,4096,768)
    const float* Wq   = (const float*)d_in[2];
    const float* Wk   = (const float*)d_in[3];
    const float* Wv   = (const float*)d_in[4];
    const float* Wo   = (const float*)d_in[5];
    float* out = (float*)d_out;

    unsigned short* base   = (unsigned short*)d_ws;
    unsigned short* xq_bf  = base;                  // 2097152
    unsigned short* xkv_bf = base + 2097152;        // 6291456
    unsigned short* wq_bf  = base + 8388608;        // 1048576
    unsigned short* wk_bf  = base + 9437184;        //  786432  \ contiguous
    unsigned short* wv_bf  = base + 10223616;       //  786432  / [2048][768]
    unsigned short* wo_bf  = base + 11010048;       // 1048576
    unsigned short* Qw     = base + 12058624;       // 2097152
    unsigned short* Kw     = base + 14155776;       // 8388608
    unsigned short* AOb    = base + 22544384;       // 2097152
    unsigned short* Vtw    = base + 30932992;       // 8388608

    dim3 blk(THREADS);
    cast_inputs<<<dim3(11776), blk, 0, stream>>>(x_q, x_kv, Wq, Wk, Wv, Wo,
                                                 xq_bf, xkv_bf, wq_bf, wk_bf, wv_bf, wo_bf);
    gemm_proj<<<dim3(1024), blk, 0, stream>>>(xkv_bf, wk_bf, Kw, Vtw, xq_bf, wq_bf, Qw);
    attn_mfma13<<<dim3(512), blk, 65536, stream>>>(Qw, Kw, Vtw, AOb);
    gemm_bf16_nt64<true><<<dim3(16, 32), blk, 0, stream>>>(AOb, wo_bf, (void*)out, 2048, 1024, 1024);
}

// Round 15
// 194.243 us; speedup vs baseline: 1.1259x; 1.1259x over previous
//
#include <hip/hip_runtime.h>
#include <hip/hip_bf16.h>
#include <cstdint>

#define THREADS 256

typedef __attribute__((ext_vector_type(8))) short bf16x8;
typedef __attribute__((ext_vector_type(4))) float f32x4;
typedef __attribute__((ext_vector_type(2))) unsigned int u32x2;

__device__ __forceinline__ void load_lds16(const void* g, void* l) {
    __builtin_amdgcn_global_load_lds(
        (const __attribute__((address_space(1))) unsigned int*)g,
        (__attribute__((address_space(3))) unsigned int*)l, 16, 0, 0);
}

__device__ __forceinline__ unsigned short f2bf(float x) {
    __hip_bfloat16 hb = __float2bfloat16(x);
    return *(unsigned short*)&hb;
}

// pack two f32 -> one u32 of 2x bf16 (lo in low half)
__device__ __forceinline__ unsigned cvt_pk_bf16(float lo, float hi) {
    unsigned r;
    asm("v_cvt_pk_bf16_f32 %0, %1, %2" : "=v"(r) : "v"(lo), "v"(hi));
    return r;
}

__device__ __forceinline__ float fexp2(float x) {
#if __has_builtin(__builtin_amdgcn_exp2f)
    return __builtin_amdgcn_exp2f(x);
#else
    return exp2f(x);
#endif
}

// distance-32 exchange: lo = [lo_low32 | hi_low32], hi = [lo_high32 | hi_high32]
__device__ __forceinline__ void swap32(unsigned& lo, unsigned& hi) {
#if __has_builtin(__builtin_amdgcn_permlane32_swap)
    u32x2 r = __builtin_amdgcn_permlane32_swap(lo, hi, false, false);
    lo = r[0]; hi = r[1];
#else
    unsigned plo = (unsigned)__shfl_xor((int)lo, 32, 64);
    unsigned phi = (unsigned)__shfl_xor((int)hi, 32, 64);
    bool up = (threadIdx.x & 32) != 0;
    unsigned nlo = up ? phi : lo;
    unsigned nhi = up ? hi : plo;
    lo = nlo; hi = nhi;
#endif
}

// distance-16 exchange: a's odd 16-rows <-> c's even 16-rows (v_permlane16_swap_b32)
__device__ __forceinline__ void swap16(unsigned& a, unsigned& c) {
#if __has_builtin(__builtin_amdgcn_permlane16_swap)
    u32x2 r = __builtin_amdgcn_permlane16_swap(a, c, false, false);
    a = r[0]; c = r[1];
#else
    unsigned as = (unsigned)__shfl_xor((int)a, 16, 64);
    unsigned cs = (unsigned)__shfl_xor((int)c, 16, 64);
    bool odd = (threadIdx.x & 16) != 0;
    unsigned na = odd ? cs : a;   // odd rows of a take c's even rows
    unsigned nc = odd ? c  : as;  // even rows of c take a's odd rows
    a = na; c = nc;
#endif
}

// ---------------------------------------------------------------------------
// Fused fp32 -> bf16 cast of the six GEMM inputs. (r13 verbatim)
// ---------------------------------------------------------------------------
__global__ __launch_bounds__(THREADS)
void cast_inputs(const float* __restrict__ xq, const float* __restrict__ xkv,
                 const float* __restrict__ wq, const float* __restrict__ wk,
                 const float* __restrict__ wv, const float* __restrict__ wo,
                 unsigned short* __restrict__ oq, unsigned short* __restrict__ okv,
                 unsigned short* __restrict__ owq, unsigned short* __restrict__ owk,
                 unsigned short* __restrict__ owv, unsigned short* __restrict__ owo) {
    const unsigned n0 = 524288, n1 = 1572864, n2 = 262144, n3 = 196608, n4 = 196608;
    unsigned i = blockIdx.x * THREADS + threadIdx.x;  // < 3014656
    const float* src; unsigned short* dst; unsigned off;
    if (i < n0)                    { src = xq;  dst = oq;  off = i; }
    else if (i < n0+n1)            { src = xkv; dst = okv; off = i - n0; }
    else if (i < n0+n1+n2)         { src = wq;  dst = owq; off = i - n0 - n1; }
    else if (i < n0+n1+n2+n3)      { src = wk;  dst = owk; off = i - n0 - n1 - n2; }
    else if (i < n0+n1+n2+n3+n4)   { src = wv;  dst = owv; off = i - n0 - n1 - n2 - n3; }
    else                           { src = wo;  dst = owo; off = i - n0 - n1 - n2 - n3 - n4; }
    float4 v = *(const float4*)(src + (size_t)off * 4);
    ushort4 o;
    o.x = f2bf(v.x); o.y = f2bf(v.y); o.z = f2bf(v.z); o.w = f2bf(v.w);
    *(ushort4*)(dst + (size_t)off * 4) = o;
}

// ---------------------------------------------------------------------------
// MERGED projection dispatch (grid 1536). r13 structure (KV on 128x128
// tiles @ 32KB LDS / 4+ blocks/CU, Q on 64x64 tiles with 512 blocks) —
// the measured optimum of its neighborhood:
//   XCD swizzle: traffic down, time neutral (round 10)
//   128^2-blocks Q / 128^2 Wo: regressed (round 7, block-count tail)
//   256x128 KV: regressed (round 13, LDS 48KB -> 3 blocks/CU occupancy cliff)
// ---------------------------------------------------------------------------
__global__ __launch_bounds__(THREADS)
void gemm_proj(const unsigned short* __restrict__ xkv, const unsigned short* __restrict__ wkv,
               unsigned short* __restrict__ Kn, unsigned short* __restrict__ Vt,
               const unsigned short* __restrict__ xq, const unsigned short* __restrict__ wq,
               unsigned short* __restrict__ Qout) {
    __shared__ __align__(16) unsigned short As[128 * 64];
    __shared__ __align__(16) unsigned short Bs[128 * 64];

    const int t    = threadIdx.x;
    const int w    = t >> 6;
    const int lane = t & 63;
    const int l15  = lane & 15;
    const int quad = lane >> 4;
    const int wm   = w & 1;
    const int wn   = w >> 1;

    if (blockIdx.x < 1024) {
        // XCD-chunked bijection (round-10 measured, neutral)
        const int xcd = blockIdx.x & 7;
        const int g   = (xcd << 3) | (blockIdx.x >> 7);   // bM-group 0..63
        const int j   = (blockIdx.x >> 3) & 15;           // bN tile 0..15
        const int bN = j * 128;
        const int bM = g * 128;
        const int Kd = 768;

        const int srow = t >> 3;
        const int scol = ((t & 7) ^ ((t >> 4) & 7)) << 3;
        const unsigned short* ga = xkv + (size_t)(bM + srow) * Kd + scol;
        const unsigned short* gb = wkv + (size_t)(bN + srow) * Kd + scol;
        const int lbase = w * 512;

        const int xr = (l15 >> 1) & 7;
        int aoff[2][4], boff[2][4];
#pragma unroll
        for (int kk = 0; kk < 2; ++kk)
#pragma unroll
            for (int mt = 0; mt < 4; ++mt) {
                aoff[kk][mt] = (wm * 64 + mt * 16 + l15) * 64 + (((kk * 4 + quad) ^ xr) << 3);
                boff[kk][mt] = (wn * 64 + mt * 16 + l15) * 64 + (((kk * 4 + quad) ^ xr) << 3);
            }

        f32x4 acc[4][4];
#pragma unroll
        for (int mt = 0; mt < 4; ++mt)
#pragma unroll
            for (int nt = 0; nt < 4; ++nt)
#pragma unroll
                for (int r = 0; r < 4; ++r) acc[mt][nt][r] = 0.f;

        for (int k0 = 0; k0 < Kd; k0 += 64) {
            __syncthreads();
#pragma unroll
            for (int it = 0; it < 4; ++it) {
                load_lds16(ga + (size_t)it * 32 * Kd + k0, &As[lbase + it * 2048]);
                load_lds16(gb + (size_t)it * 32 * Kd + k0, &Bs[lbase + it * 2048]);
            }
            __syncthreads();

#pragma unroll
            for (int kk = 0; kk < 2; ++kk) {
                bf16x8 af[4], bf[4];
#pragma unroll
                for (int mt = 0; mt < 4; ++mt) af[mt] = *(const bf16x8*)&As[aoff[kk][mt]];
#pragma unroll
                for (int nt = 0; nt < 4; ++nt) bf[nt] = *(const bf16x8*)&Bs[boff[kk][nt]];
#pragma unroll
                for (int mt = 0; mt < 4; ++mt)
#pragma unroll
                    for (int nt = 0; nt < 4; ++nt)
                        acc[mt][nt] = __builtin_amdgcn_mfma_f32_16x16x32_bf16(af[mt], bf[nt], acc[mt][nt], 0, 0, 0);
            }
        }

        const int rbase = bM + wm * 64;
        const int b  = rbase >> 12;
        const int h  = (rbase & 4095) >> 8;
        if (bN < 1024) {
            const int G = (bN + wn * 64) >> 6;
            unsigned short* kp = Kn + (size_t)(b * 16 + h) * 262144 + (size_t)G * 256 * 64 + l15;
#pragma unroll
            for (int mt = 0; mt < 4; ++mt)
#pragma unroll
                for (int r = 0; r < 4; ++r) {
                    int u = (rbase & 255) + mt * 16 + quad * 4 + r;
                    unsigned short* cp = kp + (size_t)u * 64;
#pragma unroll
                    for (int nt = 0; nt < 4; ++nt) cp[nt * 16] = f2bf(acc[mt][nt][r]);
                }
        } else {
            const int Gv = (bN - 1024 + wn * 64) >> 6;
            unsigned short* vp = Vt + (size_t)(b * 16 + h) * 262144 + (size_t)Gv * 256;
#pragma unroll
            for (int nt = 0; nt < 4; ++nt) {
                int d = nt * 16 + l15;
#pragma unroll
                for (int mt = 0; mt < 4; ++mt) {
                    int u = (rbase & 255) + mt * 16 + quad * 4;
                    ushort4 pk;
                    pk.x = f2bf(acc[mt][nt][0]);
                    pk.y = f2bf(acc[mt][nt][1]);
                    pk.z = f2bf(acc[mt][nt][2]);
                    pk.w = f2bf(acc[mt][nt][3]);
                    *(ushort4*)(vp + (size_t)d * 4096 + u) = pk;
                }
            }
        }
    } else {
        const int id = blockIdx.x - 1024;           // 0..511
        const int bN = (id & 15) * 64;
        const int bM = (id >> 4) * 64;
        const int Kd = 1024, N = 1024;

        const int srow = t >> 3;
        const int scol = ((t & 7) ^ ((t >> 3) & 7)) << 3;
        const unsigned short* ga = xq + (size_t)(bM + srow) * Kd + scol;
        const unsigned short* gb = wq + (size_t)(bN + srow) * Kd + scol;
        const int lbase = w * 512;

        int aoff[2][2], boff[2][2];
#pragma unroll
        for (int kk = 0; kk < 2; ++kk)
#pragma unroll
            for (int mt = 0; mt < 2; ++mt) {
                aoff[kk][mt] = (wm * 32 + mt * 16 + l15) * 64 + (((kk * 4 + quad) ^ (l15 & 7)) << 3);
                boff[kk][mt] = (wn * 32 + mt * 16 + l15) * 64 + (((kk * 4 + quad) ^ (l15 & 7)) << 3);
            }

        f32x4 acc[2][2];
#pragma unroll
        for (int mt = 0; mt < 2; ++mt)
#pragma unroll
            for (int nt = 0; nt < 2; ++nt)
#pragma unroll
                for (int r = 0; r < 4; ++r) acc[mt][nt][r] = 0.f;

        for (int k0 = 0; k0 < Kd; k0 += 64) {
            __syncthreads();
#pragma unroll
            for (int it = 0; it < 2; ++it) {
                load_lds16(ga + (size_t)it * 32 * Kd + k0, &As[lbase + it * 2048]);
                load_lds16(gb + (size_t)it * 32 * Kd + k0, &Bs[lbase + it * 2048]);
            }
            __syncthreads();

#pragma unroll
            for (int kk = 0; kk < 2; ++kk) {
                bf16x8 af[2], bf[2];
#pragma unroll
                for (int mt = 0; mt < 2; ++mt) af[mt] = *(const bf16x8*)&As[aoff[kk][mt]];
#pragma unroll
                for (int nt = 0; nt < 2; ++nt) bf[nt] = *(const bf16x8*)&Bs[boff[kk][nt]];
#pragma unroll
                for (int mt = 0; mt < 2; ++mt)
#pragma unroll
                    for (int nt = 0; nt < 2; ++nt)
                        acc[mt][nt] = __builtin_amdgcn_mfma_f32_16x16x32_bf16(af[mt], bf[nt], acc[mt][nt], 0, 0, 0);
            }
        }

#pragma unroll
        for (int mt = 0; mt < 2; ++mt)
#pragma unroll
            for (int r = 0; r < 4; ++r) {
                int row = bM + wm * 32 + mt * 16 + quad * 4 + r;
                int col = bN + wn * 32 + l15;
                unsigned short* cp = Qout + (size_t)row * N + col;
#pragma unroll
                for (int nt = 0; nt < 2; ++nt) cp[nt * 16] = f2bf(acc[mt][nt][r]);
            }
    }
}

// ---------------------------------------------------------------------------
// 64x64-tile bf16 MFMA GEMM (Wo projection). r13 verbatim — 512-block
// 64x64 beats the 128-block 128x128 variant at this size (round-7 data).
// ---------------------------------------------------------------------------
template <bool OUTF32>
__global__ __launch_bounds__(THREADS)
void gemm_bf16_nt64(const unsigned short* __restrict__ A, const unsigned short* __restrict__ W,
                    void* __restrict__ Cout, int M, int N, int Kd) {
    __shared__ __align__(16) unsigned short As[64 * 64];
    __shared__ __align__(16) unsigned short Bs[64 * 64];

    const int t    = threadIdx.x;
    const int w    = t >> 6;
    const int lane = t & 63;
    const int l15  = lane & 15;
    const int quad = lane >> 4;
    const int wm   = w & 1;
    const int wn   = w >> 1;
    const int bM = blockIdx.y * 64;
    const int bN = blockIdx.x * 64;

    const int srow = t >> 3;
    const int scol = ((t & 7) ^ ((t >> 3) & 7)) << 3;
    const unsigned short* ga = A + (size_t)(bM + srow) * Kd + scol;
    const unsigned short* gb = W + (size_t)(bN + srow) * Kd + scol;
    const int lbase = w * 512;

    int aoff[2][2], boff[2][2];
#pragma unroll
    for (int kk = 0; kk < 2; ++kk)
#pragma unroll
        for (int mt = 0; mt < 2; ++mt) {
            aoff[kk][mt] = (wm * 32 + mt * 16 + l15) * 64 + (((kk * 4 + quad) ^ (l15 & 7)) << 3);
            boff[kk][mt] = (wn * 32 + mt * 16 + l15) * 64 + (((kk * 4 + quad) ^ (l15 & 7)) << 3);
        }

    f32x4 acc[2][2];
#pragma unroll
    for (int mt = 0; mt < 2; ++mt)
#pragma unroll
        for (int nt = 0; nt < 2; ++nt)
#pragma unroll
            for (int r = 0; r < 4; ++r) acc[mt][nt][r] = 0.f;

    for (int k0 = 0; k0 < Kd; k0 += 64) {
        __syncthreads();
#pragma unroll
        for (int it = 0; it < 2; ++it) {
            load_lds16(ga + (size_t)it * 32 * Kd + k0, &As[lbase + it * 2048]);
            load_lds16(gb + (size_t)it * 32 * Kd + k0, &Bs[lbase + it * 2048]);
        }
        __syncthreads();

#pragma unroll
        for (int kk = 0; kk < 2; ++kk) {
            bf16x8 af[2], bf[2];
#pragma unroll
            for (int mt = 0; mt < 2; ++mt) af[mt] = *(const bf16x8*)&As[aoff[kk][mt]];
#pragma unroll
            for (int nt = 0; nt < 2; ++nt) bf[nt] = *(const bf16x8*)&Bs[boff[kk][nt]];
#pragma unroll
            for (int mt = 0; mt < 2; ++mt)
#pragma unroll
                for (int nt = 0; nt < 2; ++nt)
                    acc[mt][nt] = __builtin_amdgcn_mfma_f32_16x16x32_bf16(af[mt], bf[nt], acc[mt][nt], 0, 0, 0);
        }
    }

#pragma unroll
    for (int mt = 0; mt < 2; ++mt)
#pragma unroll
        for (int r = 0; r < 4; ++r) {
            int row = bM + wm * 32 + mt * 16 + quad * 4 + r;
            int col = bN + wn * 32 + l15;
            if (OUTF32) {
                float* cp = (float*)Cout + (size_t)row * N + col;
#pragma unroll
                for (int nt = 0; nt < 2; ++nt) cp[nt * 16] = acc[mt][nt][r];
            } else {
                unsigned short* cp = (unsigned short*)Cout + (size_t)row * N + col;
#pragma unroll
                for (int nt = 0; nt < 2; ++nt) cp[nt * 16] = f2bf(acc[mt][nt][r]);
            }
        }
}

// ---------------------------------------------------------------------------
// Flash attention v13: v10 structure + DEPTH-2 LDS DOUBLE-BUFFER.
//  (round-5/round-10 verified: ~53 us; frozen — grid-capped at 2 blocks/CU,
//  splits falsified in rounds 3-4)
// ---------------------------------------------------------------------------
__global__ __launch_bounds__(THREADS, 2)
void attn_mfma13(const unsigned short* __restrict__ Q, const unsigned short* __restrict__ K,
                 const unsigned short* __restrict__ Vt, unsigned short* __restrict__ AO) {
    extern __shared__ __align__(16) unsigned short sm[];
    // Ks buf0: [0,8192), Ks buf1: [8192,16384)
    // Vs buf0: [16384,24576), Vs buf1: [24576,32768)   (shorts; total 64 KB)
    float* OS = (float*)sm;               // epilogue overlay: 3 x [64d][68q] f32
    float* Lw = (float*)(sm + 26624);     // 256 f32

    const int bid  = blockIdx.x;          // 0..511
    const int slot = bid >> 3;
    const int qq   = slot & 15;
    const int hh   = (bid & 7) + 8 * (slot >> 4);
    const int q0 = qq * 64;
    const int h  = hh & 15;
    const int b  = hh >> 4;

    const int t    = threadIdx.x;
    const int w    = t >> 6;              // kv-quarter owner
    const int lane = t & 63;
    const int l15  = lane & 15;
    const int quad = lane >> 4;

    const unsigned short* Qh = Q + (size_t)b * 1048576 + (size_t)h * 65536 + (size_t)q0 * 64;
    const unsigned short* Kh = K + (size_t)b * 4194304 + (size_t)h * 262144;
    const unsigned short* Vh = Vt + (size_t)(b * 16 + h) * 262144;

    bf16x8 Qb[4][2];
#pragma unroll
    for (int qt = 0; qt < 4; ++qt)
#pragma unroll
        for (int kk = 0; kk < 2; ++kk)
            Qb[qt][kk] = *(const bf16x8*)(Qh + (size_t)(qt * 16 + l15) * 64 + kk * 32 + quad * 8);

    // wave-private staging pointers (v10 layout)
    const unsigned short* gKw = Kh + (size_t)(w * 32 + (lane >> 3)) * 64
                                   + (((lane & 7) ^ ((lane >> 3) & 7)) << 3);
    const unsigned short* gVw = Vh + (size_t)(lane >> 2) * 4096 + w * 32
                                   + (((lane & 3) ^ ((lane >> 2) & 3)) << 3);
    const int ldsK = w * 2048;            // + it*512 (shorts), within a K buffer
    const int ldsV = w * 2048;            // + it*512 (shorts), within a V buffer

    int koff[2][2];
#pragma unroll
    for (int kvt = 0; kvt < 2; ++kvt)
#pragma unroll
        for (int kk = 0; kk < 2; ++kk)
            koff[kvt][kk] = (w * 32 + kvt * 16 + l15) * 64 + (((kk * 4 + quad) ^ (l15 & 7)) << 3);
    int voff[4];
#pragma unroll
    for (int dt = 0; dt < 4; ++dt)
        voff[dt] = w * 2048 + (dt * 16 + l15) * 32 + ((quad ^ (l15 & 3)) << 3);

    f32x4 Oacc[4][4];
#pragma unroll
    for (int qt = 0; qt < 4; ++qt)
#pragma unroll
        for (int dt = 0; dt < 4; ++dt)
#pragma unroll
            for (int r = 0; r < 4; ++r) Oacc[qt][dt][r] = 0.f;
    float lsum[4] = {0.f, 0.f, 0.f, 0.f};

    // exp(S/64) == exp2(S * log2(e)/64): single mul feeding v_exp_f32
    const float e2s = 0.022542110013890053f;

    // ---- prologue: stage chunks 0 and 1 (16 loads in flight = steady state) ----
#pragma unroll
    for (int it = 0; it < 4; ++it)
        load_lds16(gKw + it * 512, &sm[ldsK + it * 512]);                       // K0 -> buf0
#pragma unroll
    for (int it = 0; it < 4; ++it)
        load_lds16(gVw + (size_t)it * 65536, &sm[16384 + ldsV + it * 512]);     // V0 -> buf0
#pragma unroll
    for (int it = 0; it < 4; ++it)
        load_lds16(gKw + 8192 + it * 512, &sm[8192 + ldsK + it * 512]);         // K1 -> buf1
#pragma unroll
    for (int it = 0; it < 4; ++it)
        load_lds16(gVw + 128 + (size_t)it * 65536, &sm[24576 + ldsV + it * 512]); // V1 -> buf1

    for (int kc = 0; kc < 32; ++kc) {
        const int buf = kc & 1;
        const int kn2 = (kc + 2) & 31;   // wrap keeps prefetch in-bounds
        const int kbase = buf * 8192;          // K buffer base (shorts)
        const int vbase = 16384 + buf * 8192;  // V buffer base (shorts)

        // queue (oldest->newest): K(kc),V(kc),K(kc+1),V(kc+1) = 16 loads
        asm volatile("s_waitcnt vmcnt(12)" ::: "memory");  // K(kc) landed

        // read ALL K frags, retire, then prefetch K(kc+2) into this (now dead) buffer
        bf16x8 ka0 = *(const bf16x8*)&sm[kbase + koff[0][0]];
        bf16x8 kb0 = *(const bf16x8*)&sm[kbase + koff[0][1]];
        bf16x8 ka1 = *(const bf16x8*)&sm[kbase + koff[1][0]];
        bf16x8 kb1 = *(const bf16x8*)&sm[kbase + koff[1][1]];
        asm volatile("s_waitcnt lgkmcnt(0)" ::: "memory"); // K frags in regs
#pragma unroll
        for (int it = 0; it < 4; ++it)
            load_lds16(gKw + (size_t)kn2 * 8192 + it * 512, &sm[kbase + ldsK + it * 512]);

        // ---- S-phase: S^T tiles, exp2, pure-permlane P transpose ----
        bf16x8 Pa[4];
#pragma unroll
        for (int qt = 0; qt < 4; ++qt) {
            f32x4 S0 = {0.f, 0.f, 0.f, 0.f};
            S0 = __builtin_amdgcn_mfma_f32_16x16x32_bf16(ka0, Qb[qt][0], S0, 0, 0, 0);
            S0 = __builtin_amdgcn_mfma_f32_16x16x32_bf16(kb0, Qb[qt][1], S0, 0, 0, 0);
            f32x4 S1 = {0.f, 0.f, 0.f, 0.f};
            S1 = __builtin_amdgcn_mfma_f32_16x16x32_bf16(ka1, Qb[qt][0], S1, 0, 0, 0);
            S1 = __builtin_amdgcn_mfma_f32_16x16x32_bf16(kb1, Qb[qt][1], S1, 0, 0, 0);
            float p0 = fexp2(S0[0] * e2s);
            float p1 = fexp2(S0[1] * e2s);
            float p2 = fexp2(S0[2] * e2s);
            float p3 = fexp2(S0[3] * e2s);
            float p4 = fexp2(S1[0] * e2s);
            float p5 = fexp2(S1[1] * e2s);
            float p6 = fexp2(S1[2] * e2s);
            float p7 = fexp2(S1[3] * e2s);
            lsum[qt] += ((p0 + p1) + (p2 + p3)) + ((p4 + p5) + (p6 + p7));
            // lane(row j = quad) holds u32 bf16-pair chunks: ca=2j cb=2j+1 cc=8+2j cd=9+2j
            unsigned ca = cvt_pk_bf16(p0, p1);
            unsigned cb = cvt_pk_bf16(p2, p3);
            unsigned cc = cvt_pk_bf16(p4, p5);
            unsigned cd = cvt_pk_bf16(p6, p7);
            // 4x4 chunk transpose entirely in permlanes (HW-verified in v12):
            swap32(ca, cc);
            swap32(cb, cd);
            swap16(ca, cc);
            swap16(cb, cd);
            union { unsigned u[4]; bf16x8 v; } pk_;
            pk_.u[0] = ca;   // chunk 4d+0
            pk_.u[1] = cb;   // chunk 4d+1
            pk_.u[2] = cc;   // chunk 4d+2
            pk_.u[3] = cd;   // chunk 4d+3
            Pa[qt] = pk_.v;  // A-frag: row=q(l15), k = kv quad*8..+7
        }

        // queue: V(kc),K(kc+1),V(kc+1),K(kc+2) = 16 loads
        asm volatile("s_waitcnt vmcnt(12)" ::: "memory");  // V(kc) landed

        // read V frags, retire, then prefetch V(kc+2) into this (now dead) buffer
        bf16x8 Vf[4];
#pragma unroll
        for (int dt = 0; dt < 4; ++dt) Vf[dt] = *(const bf16x8*)&sm[vbase + voff[dt]];
        asm volatile("s_waitcnt lgkmcnt(0)" ::: "memory"); // V frags in regs
#pragma unroll
        for (int it = 0; it < 4; ++it)
            load_lds16(gVw + (size_t)kn2 * 128 + (size_t)it * 65536, &sm[vbase + ldsV + it * 512]);

        // ---- O += P @ V over this wave's 32 kv (pure-MFMA cluster) ----
        __builtin_amdgcn_s_setprio(1);
#pragma unroll
        for (int qt = 0; qt < 4; ++qt)
#pragma unroll
            for (int dt = 0; dt < 4; ++dt)
                Oacc[qt][dt] = __builtin_amdgcn_mfma_f32_16x16x32_bf16(Pa[qt], Vf[dt], Oacc[qt][dt], 0, 0, 0);
        __builtin_amdgcn_s_setprio(0);
    }

    // ---- epilogue (v9 verbatim; first barrier drains the wrap prefetches) ----
#pragma unroll
    for (int qt = 0; qt < 4; ++qt) {
        float v = lsum[qt];
        v += __shfl_xor(v, 16);
        v += __shfl_xor(v, 32);
        lsum[qt] = v;
    }
    __syncthreads();   // (1) all waves done with Ks/Vs; DMA queue drained
    if (lane < 16) {
#pragma unroll
        for (int qt = 0; qt < 4; ++qt)
            Lw[w * 64 + qt * 16 + lane] = lsum[qt];
    }
    if (w > 0) {
        float* myOS = OS + (w - 1) * 4352;
#pragma unroll
        for (int qt = 0; qt < 4; ++qt)
#pragma unroll
            for (int dt = 0; dt < 4; ++dt)
                *(f32x4*)&myOS[(dt * 16 + l15) * 68 + qt * 16 + quad * 4] = Oacc[qt][dt];
    }
    __syncthreads();   // (2) partials + Lw visible
    if (w == 0) {
#pragma unroll
        for (int qt = 0; qt < 4; ++qt) {
            f32x4 lv = *(const f32x4*)&Lw[qt * 16 + quad * 4];
            lv += *(const f32x4*)&Lw[64 + qt * 16 + quad * 4];
            lv += *(const f32x4*)&Lw[128 + qt * 16 + quad * 4];
            lv += *(const f32x4*)&Lw[192 + qt * 16 + quad * 4];
            f32x4 inv;
#pragma unroll
            for (int r = 0; r < 4; ++r) inv[r] = 1.0f / lv[r];
#pragma unroll
            for (int dt = 0; dt < 4; ++dt) {
                f32x4 o = Oacc[qt][dt];
                int os = (dt * 16 + l15) * 68 + qt * 16 + quad * 4;
                o += *(const f32x4*)&OS[os];
                o += *(const f32x4*)&OS[4352 + os];
                o += *(const f32x4*)&OS[8704 + os];
#pragma unroll
                for (int r = 0; r < 4; ++r) {
                    int q = qt * 16 + quad * 4 + r;
                    AO[(size_t)b * 1048576 + (size_t)(q0 + q) * 1024 + (h << 6) + dt * 16 + l15]
                        = f2bf(o[r] * inv[r]);
                }
            }
        }
    }
}

// ---------------------------------------------------------------------------
extern "C" void kernel_launch(void* const* d_in, const int* in_sizes, int n_in,
                              void* d_out, int out_size, void* d_ws, size_t ws_size,
                              hipStream_t stream) {
    const float* x_q  = (const float*)d_in[0];  // (2,1024,1024)
    const float* x_kv = (const float*)d_in[1];  // (2,4096,768)
    const float* Wq   = (const float*)d_in[2];
    const float* Wk   = (const float*)d_in[3];
    const float* Wv   = (const float*)d_in[4];
    const float* Wo   = (const float*)d_in[5];
    float* out = (float*)d_out;

    unsigned short* base   = (unsigned short*)d_ws;
    unsigned short* xq_bf  = base;                  // 2097152
    unsigned short* xkv_bf = base + 2097152;        // 6291456
    unsigned short* wq_bf  = base + 8388608;        // 1048576
    unsigned short* wk_bf  = base + 9437184;        //  786432  \ contiguous
    unsigned short* wv_bf  = base + 10223616;       //  786432  / [2048][768]
    unsigned short* wo_bf  = base + 11010048;       // 1048576
    unsigned short* Qw     = base + 12058624;       // 2097152
    unsigned short* Kw     = base + 14155776;       // 8388608
    unsigned short* AOb    = base + 22544384;       // 2097152
    unsigned short* Vtw    = base + 30932992;       // 8388608

    dim3 blk(THREADS);
    cast_inputs<<<dim3(11776), blk, 0, stream>>>(x_q, x_kv, Wq, Wk, Wv, Wo,
                                                 xq_bf, xkv_bf, wq_bf, wk_bf, wv_bf, wo_bf);
    gemm_proj<<<dim3(1536), blk, 0, stream>>>(xkv_bf, wk_bf, Kw, Vtw, xq_bf, wq_bf, Qw);
    attn_mfma13<<<dim3(512), blk, 65536, stream>>>(Qw, Kw, Vtw, AOb);
    gemm_bf16_nt64<true><<<dim3(16, 32), blk, 0, stream>>>(AOb, wo_bf, (void*)out, 2048, 1024, 1024);
}

// Round 16
// 193.795 us; speedup vs baseline: 1.1285x; 1.0023x over previous
//
#include <hip/hip_runtime.h>
#include <hip/hip_bf16.h>
#include <cstdint>

#define THREADS 256

typedef __attribute__((ext_vector_type(8))) short bf16x8;
typedef __attribute__((ext_vector_type(4))) float f32x4;
typedef __attribute__((ext_vector_type(2))) unsigned int u32x2;

__device__ __forceinline__ void load_lds16(const void* g, void* l) {
    __builtin_amdgcn_global_load_lds(
        (const __attribute__((address_space(1))) unsigned int*)g,
        (__attribute__((address_space(3))) unsigned int*)l, 16, 0, 0);
}

__device__ __forceinline__ unsigned short f2bf(float x) {
    __hip_bfloat16 hb = __float2bfloat16(x);
    return *(unsigned short*)&hb;
}

// pack two f32 -> one u32 of 2x bf16 (lo in low half)
__device__ __forceinline__ unsigned cvt_pk_bf16(float lo, float hi) {
    unsigned r;
    asm("v_cvt_pk_bf16_f32 %0, %1, %2" : "=v"(r) : "v"(lo), "v"(hi));
    return r;
}

__device__ __forceinline__ float fexp2(float x) {
#if __has_builtin(__builtin_amdgcn_exp2f)
    return __builtin_amdgcn_exp2f(x);
#else
    return exp2f(x);
#endif
}

// distance-32 exchange: lo = [lo_low32 | hi_low32], hi = [lo_high32 | hi_high32]
__device__ __forceinline__ void swap32(unsigned& lo, unsigned& hi) {
#if __has_builtin(__builtin_amdgcn_permlane32_swap)
    u32x2 r = __builtin_amdgcn_permlane32_swap(lo, hi, false, false);
    lo = r[0]; hi = r[1];
#else
    unsigned plo = (unsigned)__shfl_xor((int)lo, 32, 64);
    unsigned phi = (unsigned)__shfl_xor((int)hi, 32, 64);
    bool up = (threadIdx.x & 32) != 0;
    unsigned nlo = up ? phi : lo;
    unsigned nhi = up ? hi : plo;
    lo = nlo; hi = nhi;
#endif
}

// distance-16 exchange: a's odd 16-rows <-> c's even 16-rows (v_permlane16_swap_b32)
__device__ __forceinline__ void swap16(unsigned& a, unsigned& c) {
#if __has_builtin(__builtin_amdgcn_permlane16_swap)
    u32x2 r = __builtin_amdgcn_permlane16_swap(a, c, false, false);
    a = r[0]; c = r[1];
#else
    unsigned as = (unsigned)__shfl_xor((int)a, 16, 64);
    unsigned cs = (unsigned)__shfl_xor((int)c, 16, 64);
    bool odd = (threadIdx.x & 16) != 0;
    unsigned na = odd ? cs : a;   // odd rows of a take c's even rows
    unsigned nc = odd ? c  : as;  // even rows of c take a's odd rows
    a = na; c = nc;
#endif
}

// ---------------------------------------------------------------------------
// Fused fp32 -> bf16 cast of the six GEMM inputs.
// Round-16 edit: 8 elements/thread (2x float4 load, 16B store), 5888 blocks.
// All segment sizes divide by 8 exactly; bijection identical scaled by 2.
// ---------------------------------------------------------------------------
__global__ __launch_bounds__(THREADS)
void cast_inputs(const float* __restrict__ xq, const float* __restrict__ xkv,
                 const float* __restrict__ wq, const float* __restrict__ wk,
                 const float* __restrict__ wv, const float* __restrict__ wo,
                 unsigned short* __restrict__ oq, unsigned short* __restrict__ okv,
                 unsigned short* __restrict__ owq, unsigned short* __restrict__ owk,
                 unsigned short* __restrict__ owv, unsigned short* __restrict__ owo) {
    // group counts of 8 floats each
    const unsigned n0 = 262144, n1 = 786432, n2 = 131072, n3 = 98304, n4 = 98304;
    unsigned i = blockIdx.x * THREADS + threadIdx.x;  // < 1507328
    const float* src; unsigned short* dst; unsigned off;
    if (i < n0)                    { src = xq;  dst = oq;  off = i; }
    else if (i < n0+n1)            { src = xkv; dst = okv; off = i - n0; }
    else if (i < n0+n1+n2)         { src = wq;  dst = owq; off = i - n0 - n1; }
    else if (i < n0+n1+n2+n3)      { src = wk;  dst = owk; off = i - n0 - n1 - n2; }
    else if (i < n0+n1+n2+n3+n4)   { src = wv;  dst = owv; off = i - n0 - n1 - n2 - n3; }
    else                           { src = wo;  dst = owo; off = i - n0 - n1 - n2 - n3 - n4; }
    float4 v0 = *(const float4*)(src + (size_t)off * 8);
    float4 v1 = *(const float4*)(src + (size_t)off * 8 + 4);
    union { unsigned short s[8]; ulonglong2 v; } o;
    o.s[0] = f2bf(v0.x); o.s[1] = f2bf(v0.y); o.s[2] = f2bf(v0.z); o.s[3] = f2bf(v0.w);
    o.s[4] = f2bf(v1.x); o.s[5] = f2bf(v1.y); o.s[6] = f2bf(v1.z); o.s[7] = f2bf(v1.w);
    *(ulonglong2*)(dst + (size_t)off * 8) = o.v;
}

// ---------------------------------------------------------------------------
// MERGED projection dispatch (grid 1536). r13 structure (KV on 128x128
// tiles @ 32KB LDS, Q on 64x64 tiles with 512 blocks) — the measured
// optimum of its neighborhood:
//   XCD swizzle: traffic down, time neutral (round 10)
//   128^2-blocks Q / 128^2 Wo: regressed (round 7, block-count tail)
//   256x128 KV: regressed (round 13, LDS 48KB -> 3 blocks/CU occupancy cliff)
// ---------------------------------------------------------------------------
__global__ __launch_bounds__(THREADS)
void gemm_proj(const unsigned short* __restrict__ xkv, const unsigned short* __restrict__ wkv,
               unsigned short* __restrict__ Kn, unsigned short* __restrict__ Vt,
               const unsigned short* __restrict__ xq, const unsigned short* __restrict__ wq,
               unsigned short* __restrict__ Qout) {
    __shared__ __align__(16) unsigned short As[128 * 64];
    __shared__ __align__(16) unsigned short Bs[128 * 64];

    const int t    = threadIdx.x;
    const int w    = t >> 6;
    const int lane = t & 63;
    const int l15  = lane & 15;
    const int quad = lane >> 4;
    const int wm   = w & 1;
    const int wn   = w >> 1;

    if (blockIdx.x < 1024) {
        // XCD-chunked bijection (round-10 measured, neutral)
        const int xcd = blockIdx.x & 7;
        const int g   = (xcd << 3) | (blockIdx.x >> 7);   // bM-group 0..63
        const int j   = (blockIdx.x >> 3) & 15;           // bN tile 0..15
        const int bN = j * 128;
        const int bM = g * 128;
        const int Kd = 768;

        const int srow = t >> 3;
        const int scol = ((t & 7) ^ ((t >> 4) & 7)) << 3;
        const unsigned short* ga = xkv + (size_t)(bM + srow) * Kd + scol;
        const unsigned short* gb = wkv + (size_t)(bN + srow) * Kd + scol;
        const int lbase = w * 512;

        const int xr = (l15 >> 1) & 7;
        int aoff[2][4], boff[2][4];
#pragma unroll
        for (int kk = 0; kk < 2; ++kk)
#pragma unroll
            for (int mt = 0; mt < 4; ++mt) {
                aoff[kk][mt] = (wm * 64 + mt * 16 + l15) * 64 + (((kk * 4 + quad) ^ xr) << 3);
                boff[kk][mt] = (wn * 64 + mt * 16 + l15) * 64 + (((kk * 4 + quad) ^ xr) << 3);
            }

        f32x4 acc[4][4];
#pragma unroll
        for (int mt = 0; mt < 4; ++mt)
#pragma unroll
            for (int nt = 0; nt < 4; ++nt)
#pragma unroll
                for (int r = 0; r < 4; ++r) acc[mt][nt][r] = 0.f;

        for (int k0 = 0; k0 < Kd; k0 += 64) {
            __syncthreads();
#pragma unroll
            for (int it = 0; it < 4; ++it) {
                load_lds16(ga + (size_t)it * 32 * Kd + k0, &As[lbase + it * 2048]);
                load_lds16(gb + (size_t)it * 32 * Kd + k0, &Bs[lbase + it * 2048]);
            }
            __syncthreads();

#pragma unroll
            for (int kk = 0; kk < 2; ++kk) {
                bf16x8 af[4], bf[4];
#pragma unroll
                for (int mt = 0; mt < 4; ++mt) af[mt] = *(const bf16x8*)&As[aoff[kk][mt]];
#pragma unroll
                for (int nt = 0; nt < 4; ++nt) bf[nt] = *(const bf16x8*)&Bs[boff[kk][nt]];
#pragma unroll
                for (int mt = 0; mt < 4; ++mt)
#pragma unroll
                    for (int nt = 0; nt < 4; ++nt)
                        acc[mt][nt] = __builtin_amdgcn_mfma_f32_16x16x32_bf16(af[mt], bf[nt], acc[mt][nt], 0, 0, 0);
            }
        }

        const int rbase = bM + wm * 64;
        const int b  = rbase >> 12;
        const int h  = (rbase & 4095) >> 8;
        if (bN < 1024) {
            const int G = (bN + wn * 64) >> 6;
            unsigned short* kp = Kn + (size_t)(b * 16 + h) * 262144 + (size_t)G * 256 * 64 + l15;
#pragma unroll
            for (int mt = 0; mt < 4; ++mt)
#pragma unroll
                for (int r = 0; r < 4; ++r) {
                    int u = (rbase & 255) + mt * 16 + quad * 4 + r;
                    unsigned short* cp = kp + (size_t)u * 64;
#pragma unroll
                    for (int nt = 0; nt < 4; ++nt) cp[nt * 16] = f2bf(acc[mt][nt][r]);
                }
        } else {
            const int Gv = (bN - 1024 + wn * 64) >> 6;
            unsigned short* vp = Vt + (size_t)(b * 16 + h) * 262144 + (size_t)Gv * 256;
#pragma unroll
            for (int nt = 0; nt < 4; ++nt) {
                int d = nt * 16 + l15;
#pragma unroll
                for (int mt = 0; mt < 4; ++mt) {
                    int u = (rbase & 255) + mt * 16 + quad * 4;
                    ushort4 pk;
                    pk.x = f2bf(acc[mt][nt][0]);
                    pk.y = f2bf(acc[mt][nt][1]);
                    pk.z = f2bf(acc[mt][nt][2]);
                    pk.w = f2bf(acc[mt][nt][3]);
                    *(ushort4*)(vp + (size_t)d * 4096 + u) = pk;
                }
            }
        }
    } else {
        const int id = blockIdx.x - 1024;           // 0..511
        const int bN = (id & 15) * 64;
        const int bM = (id >> 4) * 64;
        const int Kd = 1024, N = 1024;

        const int srow = t >> 3;
        const int scol = ((t & 7) ^ ((t >> 3) & 7)) << 3;
        const unsigned short* ga = xq + (size_t)(bM + srow) * Kd + scol;
        const unsigned short* gb = wq + (size_t)(bN + srow) * Kd + scol;
        const int lbase = w * 512;

        int aoff[2][2], boff[2][2];
#pragma unroll
        for (int kk = 0; kk < 2; ++kk)
#pragma unroll
            for (int mt = 0; mt < 2; ++mt) {
                aoff[kk][mt] = (wm * 32 + mt * 16 + l15) * 64 + (((kk * 4 + quad) ^ (l15 & 7)) << 3);
                boff[kk][mt] = (wn * 32 + mt * 16 + l15) * 64 + (((kk * 4 + quad) ^ (l15 & 7)) << 3);
            }

        f32x4 acc[2][2];
#pragma unroll
        for (int mt = 0; mt < 2; ++mt)
#pragma unroll
            for (int nt = 0; nt < 2; ++nt)
#pragma unroll
                for (int r = 0; r < 4; ++r) acc[mt][nt][r] = 0.f;

        for (int k0 = 0; k0 < Kd; k0 += 64) {
            __syncthreads();
#pragma unroll
            for (int it = 0; it < 2; ++it) {
                load_lds16(ga + (size_t)it * 32 * Kd + k0, &As[lbase + it * 2048]);
                load_lds16(gb + (size_t)it * 32 * Kd + k0, &Bs[lbase + it * 2048]);
            }
            __syncthreads();

#pragma unroll
            for (int kk = 0; kk < 2; ++kk) {
                bf16x8 af[2], bf[2];
#pragma unroll
                for (int mt = 0; mt < 2; ++mt) af[mt] = *(const bf16x8*)&As[aoff[kk][mt]];
#pragma unroll
                for (int nt = 0; nt < 2; ++nt) bf[nt] = *(const bf16x8*)&Bs[boff[kk][nt]];
#pragma unroll
                for (int mt = 0; mt < 2; ++mt)
#pragma unroll
                    for (int nt = 0; nt < 2; ++nt)
                        acc[mt][nt] = __builtin_amdgcn_mfma_f32_16x16x32_bf16(af[mt], bf[nt], acc[mt][nt], 0, 0, 0);
            }
        }

#pragma unroll
        for (int mt = 0; mt < 2; ++mt)
#pragma unroll
            for (int r = 0; r < 4; ++r) {
                int row = bM + wm * 32 + mt * 16 + quad * 4 + r;
                int col = bN + wn * 32 + l15;
                unsigned short* cp = Qout + (size_t)row * N + col;
#pragma unroll
                for (int nt = 0; nt < 2; ++nt) cp[nt * 16] = f2bf(acc[mt][nt][r]);
            }
    }
}

// ---------------------------------------------------------------------------
// 64x64-tile bf16 MFMA GEMM (Wo projection). r13 verbatim — 512-block
// 64x64 beats the 128-block 128x128 variant at this size (round-7 data).
// ---------------------------------------------------------------------------
template <bool OUTF32>
__global__ __launch_bounds__(THREADS)
void gemm_bf16_nt64(const unsigned short* __restrict__ A, const unsigned short* __restrict__ W,
                    void* __restrict__ Cout, int M, int N, int Kd) {
    __shared__ __align__(16) unsigned short As[64 * 64];
    __shared__ __align__(16) unsigned short Bs[64 * 64];

    const int t    = threadIdx.x;
    const int w    = t >> 6;
    const int lane = t & 63;
    const int l15  = lane & 15;
    const int quad = lane >> 4;
    const int wm   = w & 1;
    const int wn   = w >> 1;
    const int bM = blockIdx.y * 64;
    const int bN = blockIdx.x * 64;

    const int srow = t >> 3;
    const int scol = ((t & 7) ^ ((t >> 3) & 7)) << 3;
    const unsigned short* ga = A + (size_t)(bM + srow) * Kd + scol;
    const unsigned short* gb = W + (size_t)(bN + srow) * Kd + scol;
    const int lbase = w * 512;

    int aoff[2][2], boff[2][2];
#pragma unroll
    for (int kk = 0; kk < 2; ++kk)
#pragma unroll
        for (int mt = 0; mt < 2; ++mt) {
            aoff[kk][mt] = (wm * 32 + mt * 16 + l15) * 64 + (((kk * 4 + quad) ^ (l15 & 7)) << 3);
            boff[kk][mt] = (wn * 32 + mt * 16 + l15) * 64 + (((kk * 4 + quad) ^ (l15 & 7)) << 3);
        }

    f32x4 acc[2][2];
#pragma unroll
    for (int mt = 0; mt < 2; ++mt)
#pragma unroll
        for (int nt = 0; nt < 2; ++nt)
#pragma unroll
            for (int r = 0; r < 4; ++r) acc[mt][nt][r] = 0.f;

    for (int k0 = 0; k0 < Kd; k0 += 64) {
        __syncthreads();
#pragma unroll
        for (int it = 0; it < 2; ++it) {
            load_lds16(ga + (size_t)it * 32 * Kd + k0, &As[lbase + it * 2048]);
            load_lds16(gb + (size_t)it * 32 * Kd + k0, &Bs[lbase + it * 2048]);
        }
        __syncthreads();

#pragma unroll
        for (int kk = 0; kk < 2; ++kk) {
            bf16x8 af[2], bf[2];
#pragma unroll
            for (int mt = 0; mt < 2; ++mt) af[mt] = *(const bf16x8*)&As[aoff[kk][mt]];
#pragma unroll
            for (int nt = 0; nt < 2; ++nt) bf[nt] = *(const bf16x8*)&Bs[boff[kk][nt]];
#pragma unroll
            for (int mt = 0; mt < 2; ++mt)
#pragma unroll
                for (int nt = 0; nt < 2; ++nt)
                    acc[mt][nt] = __builtin_amdgcn_mfma_f32_16x16x32_bf16(af[mt], bf[nt], acc[mt][nt], 0, 0, 0);
        }
    }

#pragma unroll
    for (int mt = 0; mt < 2; ++mt)
#pragma unroll
        for (int r = 0; r < 4; ++r) {
            int row = bM + wm * 32 + mt * 16 + quad * 4 + r;
            int col = bN + wn * 32 + l15;
            if (OUTF32) {
                float* cp = (float*)Cout + (size_t)row * N + col;
#pragma unroll
                for (int nt = 0; nt < 2; ++nt) cp[nt * 16] = acc[mt][nt][r];
            } else {
                unsigned short* cp = (unsigned short*)Cout + (size_t)row * N + col;
#pragma unroll
                for (int nt = 0; nt < 2; ++nt) cp[nt * 16] = f2bf(acc[mt][nt][r]);
            }
        }
}

// ---------------------------------------------------------------------------
// Flash attention v13: v10 structure + DEPTH-2 LDS DOUBLE-BUFFER.
//  (rounds 5/10/15 verified: ~53-54 us; frozen — grid-capped at 2 blocks/CU,
//  splits falsified in rounds 3-4)
// ---------------------------------------------------------------------------
__global__ __launch_bounds__(THREADS, 2)
void attn_mfma13(const unsigned short* __restrict__ Q, const unsigned short* __restrict__ K,
                 const unsigned short* __restrict__ Vt, unsigned short* __restrict__ AO) {
    extern __shared__ __align__(16) unsigned short sm[];
    // Ks buf0: [0,8192), Ks buf1: [8192,16384)
    // Vs buf0: [16384,24576), Vs buf1: [24576,32768)   (shorts; total 64 KB)
    float* OS = (float*)sm;               // epilogue overlay: 3 x [64d][68q] f32
    float* Lw = (float*)(sm + 26624);     // 256 f32

    const int bid  = blockIdx.x;          // 0..511
    const int slot = bid >> 3;
    const int qq   = slot & 15;
    const int hh   = (bid & 7) + 8 * (slot >> 4);
    const int q0 = qq * 64;
    const int h  = hh & 15;
    const int b  = hh >> 4;

    const int t    = threadIdx.x;
    const int w    = t >> 6;              // kv-quarter owner
    const int lane = t & 63;
    const int l15  = lane & 15;
    const int quad = lane >> 4;

    const unsigned short* Qh = Q + (size_t)b * 1048576 + (size_t)h * 65536 + (size_t)q0 * 64;
    const unsigned short* Kh = K + (size_t)b * 4194304 + (size_t)h * 262144;
    const unsigned short* Vh = Vt + (size_t)(b * 16 + h) * 262144;

    bf16x8 Qb[4][2];
#pragma unroll
    for (int qt = 0; qt < 4; ++qt)
#pragma unroll
        for (int kk = 0; kk < 2; ++kk)
            Qb[qt][kk] = *(const bf16x8*)(Qh + (size_t)(qt * 16 + l15) * 64 + kk * 32 + quad * 8);

    // wave-private staging pointers (v10 layout)
    const unsigned short* gKw = Kh + (size_t)(w * 32 + (lane >> 3)) * 64
                                   + (((lane & 7) ^ ((lane >> 3) & 7)) << 3);
    const unsigned short* gVw = Vh + (size_t)(lane >> 2) * 4096 + w * 32
                                   + (((lane & 3) ^ ((lane >> 2) & 3)) << 3);
    const int ldsK = w * 2048;            // + it*512 (shorts), within a K buffer
    const int ldsV = w * 2048;            // + it*512 (shorts), within a V buffer

    int koff[2][2];
#pragma unroll
    for (int kvt = 0; kvt < 2; ++kvt)
#pragma unroll
        for (int kk = 0; kk < 2; ++kk)
            koff[kvt][kk] = (w * 32 + kvt * 16 + l15) * 64 + (((kk * 4 + quad) ^ (l15 & 7)) << 3);
    int voff[4];
#pragma unroll
    for (int dt = 0; dt < 4; ++dt)
        voff[dt] = w * 2048 + (dt * 16 + l15) * 32 + ((quad ^ (l15 & 3)) << 3);

    f32x4 Oacc[4][4];
#pragma unroll
    for (int qt = 0; qt < 4; ++qt)
#pragma unroll
        for (int dt = 0; dt < 4; ++dt)
#pragma unroll
            for (int r = 0; r < 4; ++r) Oacc[qt][dt][r] = 0.f;
    float lsum[4] = {0.f, 0.f, 0.f, 0.f};

    // exp(S/64) == exp2(S * log2(e)/64): single mul feeding v_exp_f32
    const float e2s = 0.022542110013890053f;

    // ---- prologue: stage chunks 0 and 1 (16 loads in flight = steady state) ----
#pragma unroll
    for (int it = 0; it < 4; ++it)
        load_lds16(gKw + it * 512, &sm[ldsK + it * 512]);                       // K0 -> buf0
#pragma unroll
    for (int it = 0; it < 4; ++it)
        load_lds16(gVw + (size_t)it * 65536, &sm[16384 + ldsV + it * 512]);     // V0 -> buf0
#pragma unroll
    for (int it = 0; it < 4; ++it)
        load_lds16(gKw + 8192 + it * 512, &sm[8192 + ldsK + it * 512]);         // K1 -> buf1
#pragma unroll
    for (int it = 0; it < 4; ++it)
        load_lds16(gVw + 128 + (size_t)it * 65536, &sm[24576 + ldsV + it * 512]); // V1 -> buf1

    for (int kc = 0; kc < 32; ++kc) {
        const int buf = kc & 1;
        const int kn2 = (kc + 2) & 31;   // wrap keeps prefetch in-bounds
        const int kbase = buf * 8192;          // K buffer base (shorts)
        const int vbase = 16384 + buf * 8192;  // V buffer base (shorts)

        // queue (oldest->newest): K(kc),V(kc),K(kc+1),V(kc+1) = 16 loads
        asm volatile("s_waitcnt vmcnt(12)" ::: "memory");  // K(kc) landed

        // read ALL K frags, retire, then prefetch K(kc+2) into this (now dead) buffer
        bf16x8 ka0 = *(const bf16x8*)&sm[kbase + koff[0][0]];
        bf16x8 kb0 = *(const bf16x8*)&sm[kbase + koff[0][1]];
        bf16x8 ka1 = *(const bf16x8*)&sm[kbase + koff[1][0]];
        bf16x8 kb1 = *(const bf16x8*)&sm[kbase + koff[1][1]];
        asm volatile("s_waitcnt lgkmcnt(0)" ::: "memory"); // K frags in regs
#pragma unroll
        for (int it = 0; it < 4; ++it)
            load_lds16(gKw + (size_t)kn2 * 8192 + it * 512, &sm[kbase + ldsK + it * 512]);

        // ---- S-phase: S^T tiles, exp2, pure-permlane P transpose ----
        bf16x8 Pa[4];
#pragma unroll
        for (int qt = 0; qt < 4; ++qt) {
            f32x4 S0 = {0.f, 0.f, 0.f, 0.f};
            S0 = __builtin_amdgcn_mfma_f32_16x16x32_bf16(ka0, Qb[qt][0], S0, 0, 0, 0);
            S0 = __builtin_amdgcn_mfma_f32_16x16x32_bf16(kb0, Qb[qt][1], S0, 0, 0, 0);
            f32x4 S1 = {0.f, 0.f, 0.f, 0.f};
            S1 = __builtin_amdgcn_mfma_f32_16x16x32_bf16(ka1, Qb[qt][0], S1, 0, 0, 0);
            S1 = __builtin_amdgcn_mfma_f32_16x16x32_bf16(kb1, Qb[qt][1], S1, 0, 0, 0);
            float p0 = fexp2(S0[0] * e2s);
            float p1 = fexp2(S0[1] * e2s);
            float p2 = fexp2(S0[2] * e2s);
            float p3 = fexp2(S0[3] * e2s);
            float p4 = fexp2(S1[0] * e2s);
            float p5 = fexp2(S1[1] * e2s);
            float p6 = fexp2(S1[2] * e2s);
            float p7 = fexp2(S1[3] * e2s);
            lsum[qt] += ((p0 + p1) + (p2 + p3)) + ((p4 + p5) + (p6 + p7));
            // lane(row j = quad) holds u32 bf16-pair chunks: ca=2j cb=2j+1 cc=8+2j cd=9+2j
            unsigned ca = cvt_pk_bf16(p0, p1);
            unsigned cb = cvt_pk_bf16(p2, p3);
            unsigned cc = cvt_pk_bf16(p4, p5);
            unsigned cd = cvt_pk_bf16(p6, p7);
            // 4x4 chunk transpose entirely in permlanes (HW-verified in v12):
            swap32(ca, cc);
            swap32(cb, cd);
            swap16(ca, cc);
            swap16(cb, cd);
            union { unsigned u[4]; bf16x8 v; } pk_;
            pk_.u[0] = ca;   // chunk 4d+0
            pk_.u[1] = cb;   // chunk 4d+1
            pk_.u[2] = cc;   // chunk 4d+2
            pk_.u[3] = cd;   // chunk 4d+3
            Pa[qt] = pk_.v;  // A-frag: row=q(l15), k = kv quad*8..+7
        }

        // queue: V(kc),K(kc+1),V(kc+1),K(kc+2) = 16 loads
        asm volatile("s_waitcnt vmcnt(12)" ::: "memory");  // V(kc) landed

        // read V frags, retire, then prefetch V(kc+2) into this (now dead) buffer
        bf16x8 Vf[4];
#pragma unroll
        for (int dt = 0; dt < 4; ++dt) Vf[dt] = *(const bf16x8*)&sm[vbase + voff[dt]];
        asm volatile("s_waitcnt lgkmcnt(0)" ::: "memory"); // V frags in regs
#pragma unroll
        for (int it = 0; it < 4; ++it)
            load_lds16(gVw + (size_t)kn2 * 128 + (size_t)it * 65536, &sm[vbase + ldsV + it * 512]);

        // ---- O += P @ V over this wave's 32 kv (pure-MFMA cluster) ----
        __builtin_amdgcn_s_setprio(1);
#pragma unroll
        for (int qt = 0; qt < 4; ++qt)
#pragma unroll
            for (int dt = 0; dt < 4; ++dt)
                Oacc[qt][dt] = __builtin_amdgcn_mfma_f32_16x16x32_bf16(Pa[qt], Vf[dt], Oacc[qt][dt], 0, 0, 0);
        __builtin_amdgcn_s_setprio(0);
    }

    // ---- epilogue (v9 verbatim; first barrier drains the wrap prefetches) ----
#pragma unroll
    for (int qt = 0; qt < 4; ++qt) {
        float v = lsum[qt];
        v += __shfl_xor(v, 16);
        v += __shfl_xor(v, 32);
        lsum[qt] = v;
    }
    __syncthreads();   // (1) all waves done with Ks/Vs; DMA queue drained
    if (lane < 16) {
#pragma unroll
        for (int qt = 0; qt < 4; ++qt)
            Lw[w * 64 + qt * 16 + lane] = lsum[qt];
    }
    if (w > 0) {
        float* myOS = OS + (w - 1) * 4352;
#pragma unroll
        for (int qt = 0; qt < 4; ++qt)
#pragma unroll
            for (int dt = 0; dt < 4; ++dt)
                *(f32x4*)&myOS[(dt * 16 + l15) * 68 + qt * 16 + quad * 4] = Oacc[qt][dt];
    }
    __syncthreads();   // (2) partials + Lw visible
    if (w == 0) {
#pragma unroll
        for (int qt = 0; qt < 4; ++qt) {
            f32x4 lv = *(const f32x4*)&Lw[qt * 16 + quad * 4];
            lv += *(const f32x4*)&Lw[64 + qt * 16 + quad * 4];
            lv += *(const f32x4*)&Lw[128 + qt * 16 + quad * 4];
            lv += *(const f32x4*)&Lw[192 + qt * 16 + quad * 4];
            f32x4 inv;
#pragma unroll
            for (int r = 0; r < 4; ++r) inv[r] = 1.0f / lv[r];
#pragma unroll
            for (int dt = 0; dt < 4; ++dt) {
                f32x4 o = Oacc[qt][dt];
                int os = (dt * 16 + l15) * 68 + qt * 16 + quad * 4;
                o += *(const f32x4*)&OS[os];
                o += *(const f32x4*)&OS[4352 + os];
                o += *(const f32x4*)&OS[8704 + os];
#pragma unroll
                for (int r = 0; r < 4; ++r) {
                    int q = qt * 16 + quad * 4 + r;
                    AO[(size_t)b * 1048576 + (size_t)(q0 + q) * 1024 + (h << 6) + dt * 16 + l15]
                        = f2bf(o[r] * inv[r]);
                }
            }
        }
    }
}

// ---------------------------------------------------------------------------
extern "C" void kernel_launch(void* const* d_in, const int* in_sizes, int n_in,
                              void* d_out, int out_size, void* d_ws, size_t ws_size,
                              hipStream_t stream) {
    const float* x_q  = (const float*)d_in[0];  // (2,1024,1024)
    const float* x_kv = (const float*)d_in[1];  // (2,4096,768)
    const float* Wq   = (const float*)d_in[2];
    const float* Wk   = (const float*)d_in[3];
    const float* Wv   = (const float*)d_in[4];
    const float* Wo   = (const float*)d_in[5];
    float* out = (float*)d_out;

    unsigned short* base   = (unsigned short*)d_ws;
    unsigned short* xq_bf  = base;                  // 2097152
    unsigned short* xkv_bf = base + 2097152;        // 6291456
    unsigned short* wq_bf  = base + 8388608;        // 1048576
    unsigned short* wk_bf  = base + 9437184;        //  786432  \ contiguous
    unsigned short* wv_bf  = base + 10223616;       //  786432  / [2048][768]
    unsigned short* wo_bf  = base + 11010048;       // 1048576
    unsigned short* Qw     = base + 12058624;       // 2097152
    unsigned short* Kw     = base + 14155776;       // 8388608
    unsigned short* AOb    = base + 22544384;       // 2097152
    unsigned short* Vtw    = base + 30932992;       // 8388608

    dim3 blk(THREADS);
    cast_inputs<<<dim3(5888), blk, 0, stream>>>(x_q, x_kv, Wq, Wk, Wv, Wo,
                                                xq_bf, xkv_bf, wq_bf, wk_bf, wv_bf, wo_bf);
    gemm_proj<<<dim3(1536), blk, 0, stream>>>(xkv_bf, wk_bf, Kw, Vtw, xq_bf, wq_bf, Qw);
    attn_mfma13<<<dim3(512), blk, 65536, stream>>>(Qw, Kw, Vtw, AOb);
    gemm_bf16_nt64<true><<<dim3(16, 32), blk, 0, stream>>>(AOb, wo_bf, (void*)out, 2048, 1024, 1024);
}